// Round 9
// baseline (470.934 us; speedup 1.0000x reference)
//
#include <hip/hip_runtime.h>
#include <hip/hip_bf16.h>
#include <math.h>

// ANI per-type MLP ensemble, MI355X bf16-MFMA.
// R13: attack the CONSTANT ~217us of non-k_mlp time (dur_us - k_mlp = 217+-2
//      in all 8 measured rounds while k_mlp swung 142..233us). k_mlp reverted
//      byte-for-byte to the proven-best R6 (142us). Pre-pipeline collapsed:
//        - k_scan (1 block, whole-GPU serial) + k_scatter -> single k_place:
//          every block redundantly reduces the 512-entry histogram (4 waves,
//          one type each), computes poff locally, then places atoms via
//          per-wave ballot + one atomicAdd per type per wave on global
//          cursors. Per-type order becomes nondeterministic -- harmless:
//          atoms are independent, and outE atomicAdd order already varies.
//        - launches 4 -> 3; no single-block kernel; boff dropped from ws.
//      Decision rule: dur <= ~300 -> pre-pipeline was the cost (keep going
//      there); dur ~= 360 -> C is harness-fixed, floor = k_mlp + C.

#define NATOMS   131072                     // 2048 * 64
#define NMOL     2048
#define AEV      384
#define NTYPES   4
#define MBLK     64                         // atoms per MLP block
#define PADTOT   (NATOMS + NTYPES * MBLK)   // 131328
#define NBLK_MLP (PADTOT / MBLK)            // 2052
#define NBLK_H   512                        // histogram blocks (256 atoms each)

// swizzled-weight layout (bf16, per type): L0 [12kt][10nt][64][8] = 61440,
// L1 [5][8][64][8] = 20480, L2 [4][6][64][8] = 12288  -> 94208 per type
#define WB_L1 61440
#define WB_L2 81920
#define WB_T  94208

typedef __attribute__((ext_vector_type(8))) short bf16x8;
typedef __attribute__((ext_vector_type(4))) float f32x4;

__device__ __forceinline__ float celu01(float v) {
  return (v > 0.f) ? v : 0.1f * (__expf(v * 10.f) - 1.f);  // v<0 => exp arg <0, safe
}
__device__ __forceinline__ unsigned short f2bf(float x) {  // RNE (bit-exact w/ HW)
  unsigned u = __float_as_uint(x);
  return (unsigned short)((u + 0x7FFFu + ((u >> 16) & 1u)) >> 16);
}
__device__ __forceinline__ unsigned int pk2(float lo, float hi) {  // v_cvt_pk_bf16_f32
  union { __hip_bfloat162 h; unsigned int u; } c;
  c.h = __float22bfloat162_rn(make_float2(lo, hi));  // x -> low 16 bits (RNE)
  return c.u;
}
__device__ __forceinline__ bf16x8 cvt8(const float4 r0, const float4 r1) {
  union { unsigned int u[4]; bf16x8 v; } c;
  c.u[0] = pk2(r0.x, r0.y);
  c.u[1] = pk2(r0.z, r0.w);
  c.u[2] = pk2(r1.x, r1.y);
  c.u[3] = pk2(r1.z, r1.w);
  return c.v;
}

// ---- fused prep: out init + perm init + weight swizzle + histogram ----------

__global__ void k_pre(const int* __restrict__ species, float* __restrict__ out,
                      int* __restrict__ perm, int* __restrict__ hist,
                      int* __restrict__ cursor,
                      const float* __restrict__ W0, const float* __restrict__ W1,
                      const float* __restrict__ W2, unsigned short* __restrict__ WB) {
  const int tid = threadIdx.x, blk = blockIdx.x;
  const int i = blk * 256 + tid;                  // grid = PADTOT/256 = 513
  perm[i] = -1;
  if (i < NATOMS) out[i] = (float)species[i];     // output 0: species passthrough
  if (i < NMOL) out[NATOMS + i] = 0.f;            // output 1: energies
  if (i < NTYPES) cursor[i] = 0;                  // placement cursors for k_place

  // weight swizzle, grid-stride over 4*WB_T elements
  for (int f = i; f < NTYPES * WB_T; f += PADTOT) {
    const int t = f / WB_T, e0 = f - t * WB_T;
    int base, NT, N;
    const float* W;
    if (e0 < WB_L1)      { base = 0;     NT = 10; N = 160; W = W0 + (size_t)t * AEV * 160; }
    else if (e0 < WB_L2) { base = WB_L1; NT = 8;  N = 128; W = W1 + (size_t)t * 160 * 128; }
    else                 { base = WB_L2; NT = 6;  N = 96;  W = W2 + (size_t)t * 128 * 96; }
    const int e = e0 - base, frag = e >> 9, r = e & 511, lane = r >> 3, j = r & 7;
    const int kt = frag / NT, nt = frag - kt * NT;
    const int k = kt * 32 + ((lane >> 4) << 3) + j, n = nt * 16 + (lane & 15);
    WB[(size_t)t * WB_T + e0] = f2bf(W[k * N + n]);
  }

  if (blk < NBLK_H) {                             // histogram (blocks 0..511)
    const int sp = species[i];
    const int wv = tid >> 6;
    __shared__ int wc[4 * NTYPES];
#pragma unroll
    for (int t = 0; t < NTYPES; ++t) {
      const unsigned long long m = __ballot(sp == t);
      if ((tid & 63) == 0) wc[wv * NTYPES + t] = __popcll(m);
    }
    __syncthreads();
    if (tid < NTYPES)
      hist[tid * NBLK_H + blk] = wc[tid] + wc[4 + tid] + wc[8 + tid] + wc[12 + tid];
  }
}

// ---- k_place: redundant histogram reduce + poff + atomic-slot scatter -------
// Replaces k_scan (1-block, whole-GPU serial) + k_scatter. Every block
// recomputes the 4 type totals (wave wv sums type wv over 512 entries) and
// the padded prefix poff -- deterministic and identical across blocks. Atoms
// are then placed with per-wave ballot compaction + one atomicAdd per type
// per wave on global cursors (order within a type nondeterministic; harmless).

__global__ void k_place(const int* __restrict__ species, const int* __restrict__ hist,
                        int* __restrict__ poff, int* __restrict__ cursor,
                        int* __restrict__ perm) {
  __shared__ int tot[NTYPES], pof[NTYPES + 1];
  const int tid = threadIdx.x, blk = blockIdx.x;
  const int wv = tid >> 6, lane = tid & 63;

  int s = 0;                                      // wave wv sums type wv
  for (int c = 0; c < 8; ++c) s += hist[wv * NBLK_H + c * 64 + lane];
  for (int off = 32; off; off >>= 1) s += __shfl_down(s, off);
  if (lane == 0) tot[wv] = s;
  __syncthreads();
  if (tid == 0) {
    int acc = 0;
    pof[0] = 0;
    for (int t = 0; t < NTYPES; ++t) {
      acc += ((tot[t] + 63) >> 6) << 6;
      pof[t + 1] = acc;
    }
    if (blk == 0)                                 // publish for k_mlp
      for (int t = 0; t <= NTYPES; ++t) poff[t] = pof[t];
  }
  __syncthreads();

  const int i = blk * 256 + tid;                  // grid = NATOMS/256 = 512
  const int sp = species[i];
#pragma unroll
  for (int t = 0; t < NTYPES; ++t) {
    const unsigned long long m = __ballot(sp == t);
    int base = 0;
    if (lane == 0 && m) base = atomicAdd(&cursor[t], (int)__popcll(m));
    base = __shfl(base, 0);
    if (sp == t) {
      const int rk = __builtin_amdgcn_mbcnt_hi((unsigned)(m >> 32),
                     __builtin_amdgcn_mbcnt_lo((unsigned)m, 0));
      perm[pof[t] + base + rk] = i;
    }
  }
}

// ---- 2-wave fused 4-layer MFMA MLP + molecule reduction (R6, proven 142us) --
// 128 threads = 2 waves; wave w owns M-tiles {2w, 2w+1} = rows [32w, 32w+32).
// A-fragments (M=16,K=32 bf16): lane holds row l&15, k = (l>>4)*8 + j, so lanes
// {x,x+16,x+32,x+48} cover one contiguous 128B line of an aev row -> coalesced
// direct global->reg loads, converted f32->bf16 in-register (v_cvt_pk).

__global__ __launch_bounds__(128) void k_mlp(
    const float* __restrict__ aev, const unsigned short* __restrict__ WB,
    const float* __restrict__ b0, const float* __restrict__ b1,
    const float* __restrict__ b2, const float* __restrict__ b3,
    const float* __restrict__ W3,
    const int* __restrict__ poff, const int* __restrict__ perm,
    float* __restrict__ outE)
{
  __shared__ __align__(16) unsigned short H[64 * 168];   // 21504 B
  __shared__ int permS[64];

  const int tid  = threadIdx.x;
  const int lane = tid & 63;
  const int wv   = __builtin_amdgcn_readfirstlane(tid >> 6);   // 0 / 1
  const int quad = lane >> 4, l15 = lane & 15;
  const int slot0 = blockIdx.x * MBLK;

  if (tid < 64) permS[tid] = perm[slot0 + tid];
  int t_ = (slot0 >= poff[1]) + (slot0 >= poff[2]) + (slot0 >= poff[3]);
  if (t_ > 3) t_ = 3;
  const int t = __builtin_amdgcn_readfirstlane(t_);
  __syncthreads();

  // per-M-tile row pointers (padded rows -> aev row 0; results discarded)
  const float* rp[2];
#pragma unroll
  for (int mtl = 0; mtl < 2; ++mtl) {
    const int ai = permS[(2 * wv + mtl) * 16 + l15];
    rp[mtl] = aev + (size_t)(ai < 0 ? 0 : ai) * AEV + quad * 8;
  }

  const bf16x8* wb0 = (const bf16x8*)(WB + (size_t)t * WB_T);
  const bf16x8* wb1 = (const bf16x8*)(WB + (size_t)t * WB_T + WB_L1);
  const bf16x8* wb2 = (const bf16x8*)(WB + (size_t)t * WB_T + WB_L2);

  // ---------------- layer 0: 384 -> 160 --------------------------------------
  f32x4 acc0[10][2];
#pragma unroll
  for (int nt = 0; nt < 10; ++nt) {
    const float b = b0[t * 160 + nt * 16 + l15];
#pragma unroll
    for (int mtl = 0; mtl < 2; ++mtl) acc0[nt][mtl] = (f32x4){b, b, b, b};
  }

  float4 raw[2][2];
#pragma unroll
  for (int mtl = 0; mtl < 2; ++mtl) {                    // prologue: ks = 0
    raw[mtl][0] = *(const float4*)(rp[mtl]);
    raw[mtl][1] = *(const float4*)(rp[mtl] + 4);
  }

  for (int ks = 0; ks < 12; ++ks) {
    const bf16x8 a0 = cvt8(raw[0][0], raw[0][1]);
    const bf16x8 a1 = cvt8(raw[1][0], raw[1][1]);
    if (ks < 11) {                                       // prefetch next K-slice
#pragma unroll
      for (int mtl = 0; mtl < 2; ++mtl) {
        const float* p = rp[mtl] + (ks + 1) * 32;
        raw[mtl][0] = *(const float4*)p;
        raw[mtl][1] = *(const float4*)(p + 4);
      }
    }
#pragma unroll
    for (int nt = 0; nt < 10; ++nt) {
      const bf16x8 w = wb0[(ks * 10 + nt) * 64 + lane];  // one load -> 2 MFMAs
      acc0[nt][0] = __builtin_amdgcn_mfma_f32_16x16x32_bf16(a0, w, acc0[nt][0], 0, 0, 0);
      acc0[nt][1] = __builtin_amdgcn_mfma_f32_16x16x32_bf16(a1, w, acc0[nt][1], 0, 0, 0);
    }
  }
#pragma unroll
  for (int nt = 0; nt < 10; ++nt)                        // H0: stride 168
#pragma unroll
    for (int mtl = 0; mtl < 2; ++mtl)
#pragma unroll
      for (int r = 0; r < 4; ++r)
        H[((2 * wv + mtl) * 16 + quad * 4 + r) * 168 + nt * 16 + l15] = f2bf(celu01(acc0[nt][mtl][r]));
  __syncthreads();                                       // H0 visible / fence

  // ---------------- layer 1: 160 -> 128 --------------------------------------
  f32x4 acc1[8][2];
#pragma unroll
  for (int nt = 0; nt < 8; ++nt) {
    const float b = b1[t * 128 + nt * 16 + l15];
#pragma unroll
    for (int mtl = 0; mtl < 2; ++mtl) acc1[nt][mtl] = (f32x4){b, b, b, b};
  }
#pragma unroll
  for (int ks = 0; ks < 5; ++ks) {
    const bf16x8 a0 = *(const bf16x8*)&H[((2 * wv + 0) * 16 + l15) * 168 + quad * 8 + ks * 32];
    const bf16x8 a1 = *(const bf16x8*)&H[((2 * wv + 1) * 16 + l15) * 168 + quad * 8 + ks * 32];
#pragma unroll
    for (int nt = 0; nt < 8; ++nt) {
      const bf16x8 w = wb1[(ks * 8 + nt) * 64 + lane];
      acc1[nt][0] = __builtin_amdgcn_mfma_f32_16x16x32_bf16(a0, w, acc1[nt][0], 0, 0, 0);
      acc1[nt][1] = __builtin_amdgcn_mfma_f32_16x16x32_bf16(a1, w, acc1[nt][1], 0, 0, 0);
    }
  }
  __syncthreads();                                       // all H0 reads done
#pragma unroll
  for (int nt = 0; nt < 8; ++nt)                         // H1: stride 136
#pragma unroll
    for (int mtl = 0; mtl < 2; ++mtl)
#pragma unroll
      for (int r = 0; r < 4; ++r)
        H[((2 * wv + mtl) * 16 + quad * 4 + r) * 136 + nt * 16 + l15] = f2bf(celu01(acc1[nt][mtl][r]));
  __syncthreads();                                       // H1 visible / fence

  // ---------------- layer 2: 128 -> 96 ---------------------------------------
  f32x4 acc2[6][2];
#pragma unroll
  for (int nt = 0; nt < 6; ++nt) {
    const float b = b2[t * 96 + nt * 16 + l15];
#pragma unroll
    for (int mtl = 0; mtl < 2; ++mtl) acc2[nt][mtl] = (f32x4){b, b, b, b};
  }
#pragma unroll
  for (int ks = 0; ks < 4; ++ks) {
    const bf16x8 a0 = *(const bf16x8*)&H[((2 * wv + 0) * 16 + l15) * 136 + quad * 8 + ks * 32];
    const bf16x8 a1 = *(const bf16x8*)&H[((2 * wv + 1) * 16 + l15) * 136 + quad * 8 + ks * 32];
#pragma unroll
    for (int nt = 0; nt < 6; ++nt) {
      const bf16x8 w = wb2[(ks * 6 + nt) * 64 + lane];
      acc2[nt][0] = __builtin_amdgcn_mfma_f32_16x16x32_bf16(a0, w, acc2[nt][0], 0, 0, 0);
      acc2[nt][1] = __builtin_amdgcn_mfma_f32_16x16x32_bf16(a1, w, acc2[nt][1], 0, 0, 0);
    }
  }
  __syncthreads();                                       // all H1 reads done
#pragma unroll
  for (int nt = 0; nt < 6; ++nt)                         // H2: stride 104
#pragma unroll
    for (int mtl = 0; mtl < 2; ++mtl)
#pragma unroll
      for (int r = 0; r < 4; ++r)
        H[((2 * wv + mtl) * 16 + quad * 4 + r) * 104 + nt * 16 + l15] = f2bf(celu01(acc2[nt][mtl][r]));
  __syncthreads();                                       // H2 visible / fence

  // ---------------- layer 3: 96 -> 1 via MFMA (w3 broadcast to all 16 cols) --
  bf16x8 w3f[3];
#pragma unroll
  for (int ks = 0; ks < 3; ++ks) {
    const float* wp = W3 + t * 96 + ks * 32 + quad * 8;  // uniform across l15
    const float4 f0 = *(const float4*)wp;
    const float4 f1 = *(const float4*)(wp + 4);
    w3f[ks] = cvt8(f0, f1);
  }
  f32x4 accE[2];
#pragma unroll
  for (int mtl = 0; mtl < 2; ++mtl) accE[mtl] = (f32x4){0.f, 0.f, 0.f, 0.f};
#pragma unroll
  for (int mtl = 0; mtl < 2; ++mtl)
#pragma unroll
    for (int ks = 0; ks < 3; ++ks) {
      const bf16x8 a = *(const bf16x8*)&H[((2 * wv + mtl) * 16 + l15) * 104 + quad * 8 + ks * 32];
      accE[mtl] = __builtin_amdgcn_mfma_f32_16x16x32_bf16(a, w3f[ks], accE[mtl], 0, 0, 0);
    }
  // accE[mtl][r] = energy of atom (2wv+mtl)*16 + quad*4 + r, identical over l15
  const float bb3 = b3[t];
#pragma unroll
  for (int mtl = 0; mtl < 2; ++mtl)
#pragma unroll
    for (int r = 0; r < 4; ++r)
      if (l15 == 0) {
        const int ai = permS[(2 * wv + mtl) * 16 + quad * 4 + r];
        if (ai >= 0) atomicAdd(&outE[ai >> 6], accE[mtl][r] + bb3);
      }
}

// ---- launch -----------------------------------------------------------------

extern "C" void kernel_launch(void* const* d_in, const int* in_sizes, int n_in,
                              void* d_out, int out_size, void* d_ws, size_t ws_size,
                              hipStream_t stream)
{
  const int*   species = (const int*)d_in[0];
  const float* aev     = (const float*)d_in[1];
  const float* W0 = (const float*)d_in[2];
  const float* b0 = (const float*)d_in[3];
  const float* W1 = (const float*)d_in[4];
  const float* b1 = (const float*)d_in[5];
  const float* W2 = (const float*)d_in[6];
  const float* b2 = (const float*)d_in[7];
  const float* W3 = (const float*)d_in[8];
  const float* b3 = (const float*)d_in[9];
  float* out = (float*)d_out;

  // ws (ints): poff[8], hist[2048], cursor[8], perm[PADTOT]; then bf16 WB
  int* poff   = (int*)d_ws;
  int* hist   = poff + 8;
  int* cursor = hist + NTYPES * NBLK_H;
  int* perm   = cursor + 8;
  unsigned short* WB = (unsigned short*)(perm + PADTOT);

  k_pre  <<<PADTOT / 256, 256, 0, stream>>>(species, out, perm, hist, cursor,
                                            W0, W1, W2, WB);
  k_place<<<NBLK_H, 256, 0, stream>>>(species, hist, poff, cursor, perm);
  k_mlp  <<<NBLK_MLP, 128, 0, stream>>>(aev, WB, b0, b1, b2, b3, W3,
                                        poff, perm, out + NATOMS);
}

// Round 10
// 358.767 us; speedup vs baseline: 1.3126x; 1.3126x over previous
//
#include <hip/hip_runtime.h>
#include <math.h>

// ANI per-type MLP ensemble, MI355X bf16-MFMA.
// R14: recovery + consolidation. R13 lessons: (a) k_mlp needs the DETERMINISTIC
//      counting-sort perm -- atomic placement scrambled within-type atom order
//      and cost k_mlp +23us with identical code; (b) k_place's 8192 atomics on
//      one cursor line serialized across XCDs (+88us). R14 reverts k_pre+k_mlp
//      byte-for-byte to the proven R2 (360.2us total / 142us k_mlp) and fuses
//      k_scan+k_scatter into ONE deterministic atomic-free k_sct:
//        - wave t reduces hist row t for the type total AND (same loads,
//          idx<blk predicate) this block's exclusive prefix -> redundant
//          per-block poff/boff, identical to the old scan's values
//        - then the original ballot scatter -> perm bit-identical to R2
//      Launches 4 -> 3; the 1-block whole-GPU-serial k_scan is gone; no
//      contention. ws: poff[8], hist[2048], perm[PADTOT], WB.

#define NATOMS   131072                     // 2048 * 64
#define NMOL     2048
#define AEV      384
#define NTYPES   4
#define MBLK     64                         // atoms per MLP block
#define PADTOT   (NATOMS + NTYPES * MBLK)   // 131328
#define NBLK_MLP (PADTOT / MBLK)            // 2052
#define NBLK_H   512                        // histogram blocks (256 atoms each)

// swizzled-weight layout (bf16, per type): L0 [12kt][10nt][64][8] = 61440,
// L1 [5][8][64][8] = 20480, L2 [4][6][64][8] = 12288  -> 94208 per type
#define WB_L1 61440
#define WB_L2 81920
#define WB_T  94208

typedef __attribute__((ext_vector_type(8))) short bf16x8;
typedef __attribute__((ext_vector_type(4))) float f32x4;

__device__ __forceinline__ float celu01(float v) {
  return (v > 0.f) ? v : 0.1f * (__expf(v * 10.f) - 1.f);  // v<0 => exp arg <0, safe
}
__device__ __forceinline__ unsigned short f2bf(float x) {  // RNE
  unsigned u = __float_as_uint(x);
  return (unsigned short)((u + 0x7FFFu + ((u >> 16) & 1u)) >> 16);
}
__device__ __forceinline__ unsigned int pk2(float lo, float hi) {  // 2x RNE packed
  unsigned a = __float_as_uint(lo), b = __float_as_uint(hi);
  a = (a + 0x7FFFu + ((a >> 16) & 1u)) >> 16;
  b = ((b + 0x7FFFu + ((b >> 16) & 1u)) >> 16) << 16;
  return a | b;
}

// ---- fused prep: out init + perm init + weight swizzle + histogram ----------

__global__ void k_pre(const int* __restrict__ species, float* __restrict__ out,
                      int* __restrict__ perm, int* __restrict__ hist,
                      const float* __restrict__ W0, const float* __restrict__ W1,
                      const float* __restrict__ W2, unsigned short* __restrict__ WB) {
  const int tid = threadIdx.x, blk = blockIdx.x;
  const int i = blk * 256 + tid;                  // grid = PADTOT/256 = 513
  perm[i] = -1;
  if (i < NATOMS) out[i] = (float)species[i];     // output 0: species passthrough
  if (i < NMOL) out[NATOMS + i] = 0.f;            // output 1: energies

  // weight swizzle, grid-stride over 4*WB_T elements
  for (int f = i; f < NTYPES * WB_T; f += PADTOT) {
    const int t = f / WB_T, e0 = f - t * WB_T;
    int base, NT, N;
    const float* W;
    if (e0 < WB_L1)      { base = 0;     NT = 10; N = 160; W = W0 + (size_t)t * AEV * 160; }
    else if (e0 < WB_L2) { base = WB_L1; NT = 8;  N = 128; W = W1 + (size_t)t * 160 * 128; }
    else                 { base = WB_L2; NT = 6;  N = 96;  W = W2 + (size_t)t * 128 * 96; }
    const int e = e0 - base, frag = e >> 9, r = e & 511, lane = r >> 3, j = r & 7;
    const int kt = frag / NT, nt = frag - kt * NT;
    const int k = kt * 32 + ((lane >> 4) << 3) + j, n = nt * 16 + (lane & 15);
    WB[(size_t)t * WB_T + e0] = f2bf(W[k * N + n]);
  }

  if (blk < NBLK_H) {                             // histogram (blocks 0..511)
    const int sp = species[i];
    const int wv = tid >> 6;
    __shared__ int wc[4 * NTYPES];
#pragma unroll
    for (int t = 0; t < NTYPES; ++t) {
      const unsigned long long m = __ballot(sp == t);
      if ((tid & 63) == 0) wc[wv * NTYPES + t] = __popcll(m);
    }
    __syncthreads();
    if (tid < NTYPES)
      hist[tid * NBLK_H + blk] = wc[tid] + wc[4 + tid] + wc[8 + tid] + wc[12 + tid];
  }
}

// ---- k_sct: fused deterministic scan + scatter (replaces k_scan+k_scatter) --
// Every block redundantly computes: wave t reduces hist row t -> type total
// AND (same loads, idx<blk predicate) the exclusive prefix for THIS block.
// poff/boff values identical to the old 1-block scan -> perm bit-identical
// to the R2 counting sort (preserves within-type ascending atom order, which
// k_mlp's aev locality depends on -- R13 lesson). No atomics anywhere.

__global__ void k_sct(const int* __restrict__ species, const int* __restrict__ hist,
                      int* __restrict__ poff, int* __restrict__ perm) {
  __shared__ int tot[NTYPES], preS[NTYPES], bofS[NTYPES];
  const int tid = threadIdx.x, blk = blockIdx.x;
  const int wv = tid >> 6, lane = tid & 63;

  int s = 0, p = 0;                               // wave wv handles type wv
  for (int c = 0; c < 8; ++c) {
    const int idx = c * 64 + lane;
    const int h = hist[wv * NBLK_H + idx];
    s += h;
    if (idx < blk) p += h;
  }
  for (int off = 32; off; off >>= 1) {
    s += __shfl_down(s, off);
    p += __shfl_down(p, off);
  }
  if (lane == 0) { tot[wv] = s; preS[wv] = p; }
  __syncthreads();
  if (tid == 0) {
    int acc = 0;
    for (int t = 0; t < NTYPES; ++t) {
      bofS[t] = acc + preS[t];                    // base[t] + excl. prefix(<blk)
      acc += ((tot[t] + 63) >> 6) << 6;
      if (blk == 0) poff[t + 1] = acc;            // publish padded prefix
    }
    if (blk == 0) poff[0] = 0;
  }
  __syncthreads();

  const int i = blk * 256 + tid;                  // grid = NATOMS/256 = 512
  const int sp = species[i];
  __shared__ int wc[4 * NTYPES];
  unsigned long long msel = 0;
#pragma unroll
  for (int t = 0; t < NTYPES; ++t) {
    const unsigned long long m = __ballot(sp == t);
    if ((tid & 63) == 0) wc[wv * NTYPES + t] = __popcll(m);
    if (sp == t) msel = m;
  }
  __syncthreads();
  int woff = 0;
  for (int w = 0; w < wv; ++w) woff += wc[w * NTYPES + sp];
  const int rk = __builtin_amdgcn_mbcnt_hi((unsigned)(msel >> 32),
                 __builtin_amdgcn_mbcnt_lo((unsigned)msel, 0));
  perm[bofS[sp] + woff + rk] = i;
}

// ---- 2-wave fused 4-layer MFMA MLP + molecule reduction (R2, proven 142us) --
// 128 threads = 2 waves; wave w owns M-tiles {2w, 2w+1} = rows [32w, 32w+32).
// A-fragments (M=16,K=32 bf16): lane holds row l&15, k = (l>>4)*8 + j, so lanes
// {x,x+16,x+32,x+48} cover one contiguous 128B line of an aev row -> coalesced
// direct global->reg loads, converted f32->bf16 in-register (packed RNE).

__global__ __launch_bounds__(128) void k_mlp(
    const float* __restrict__ aev, const unsigned short* __restrict__ WB,
    const float* __restrict__ b0, const float* __restrict__ b1,
    const float* __restrict__ b2, const float* __restrict__ b3,
    const float* __restrict__ W3,
    const int* __restrict__ poff, const int* __restrict__ perm,
    float* __restrict__ outE)
{
  __shared__ __align__(16) unsigned short H[64 * 168];   // 21504 B
  __shared__ int permS[64];

  const int tid  = threadIdx.x;
  const int lane = tid & 63;
  const int wv   = __builtin_amdgcn_readfirstlane(tid >> 6);   // 0 / 1
  const int quad = lane >> 4, l15 = lane & 15;
  const int slot0 = blockIdx.x * MBLK;

  if (tid < 64) permS[tid] = perm[slot0 + tid];
  int t_ = (slot0 >= poff[1]) + (slot0 >= poff[2]) + (slot0 >= poff[3]);
  if (t_ > 3) t_ = 3;
  const int t = __builtin_amdgcn_readfirstlane(t_);
  __syncthreads();

  // per-M-tile row pointers (padded rows -> aev row 0; results discarded)
  const float* rp[2];
#pragma unroll
  for (int mtl = 0; mtl < 2; ++mtl) {
    const int ai = permS[(2 * wv + mtl) * 16 + l15];
    rp[mtl] = aev + (size_t)(ai < 0 ? 0 : ai) * AEV + quad * 8;
  }

  const bf16x8* wb0 = (const bf16x8*)(WB + (size_t)t * WB_T);
  const bf16x8* wb1 = (const bf16x8*)(WB + (size_t)t * WB_T + WB_L1);
  const bf16x8* wb2 = (const bf16x8*)(WB + (size_t)t * WB_T + WB_L2);

  union U8 { unsigned int u[4]; bf16x8 v; };

  // ---------------- layer 0: 384 -> 160 --------------------------------------
  f32x4 acc0[10][2];
#pragma unroll
  for (int nt = 0; nt < 10; ++nt) {
    const float b = b0[t * 160 + nt * 16 + l15];
#pragma unroll
    for (int mtl = 0; mtl < 2; ++mtl) acc0[nt][mtl] = (f32x4){b, b, b, b};
  }

  float4 raw[2][2];
#pragma unroll
  for (int mtl = 0; mtl < 2; ++mtl) {                    // prologue: ks = 0
    raw[mtl][0] = *(const float4*)(rp[mtl]);
    raw[mtl][1] = *(const float4*)(rp[mtl] + 4);
  }

  for (int ks = 0; ks < 12; ++ks) {
    bf16x8 a[2];
#pragma unroll
    for (int mtl = 0; mtl < 2; ++mtl) {                  // convert current
      U8 c;
      c.u[0] = pk2(raw[mtl][0].x, raw[mtl][0].y);
      c.u[1] = pk2(raw[mtl][0].z, raw[mtl][0].w);
      c.u[2] = pk2(raw[mtl][1].x, raw[mtl][1].y);
      c.u[3] = pk2(raw[mtl][1].z, raw[mtl][1].w);
      a[mtl] = c.v;
    }
    if (ks < 11) {                                       // prefetch next K-slice
#pragma unroll
      for (int mtl = 0; mtl < 2; ++mtl) {
        const float* p = rp[mtl] + (ks + 1) * 32;
        raw[mtl][0] = *(const float4*)p;
        raw[mtl][1] = *(const float4*)(p + 4);
      }
    }
#pragma unroll
    for (int nt = 0; nt < 10; ++nt) {
      const bf16x8 w = wb0[(ks * 10 + nt) * 64 + lane];  // one load -> 2 MFMAs
#pragma unroll
      for (int mtl = 0; mtl < 2; ++mtl)
        acc0[nt][mtl] = __builtin_amdgcn_mfma_f32_16x16x32_bf16(a[mtl], w, acc0[nt][mtl], 0, 0, 0);
    }
  }
#pragma unroll
  for (int nt = 0; nt < 10; ++nt)                        // H0: stride 168
#pragma unroll
    for (int mtl = 0; mtl < 2; ++mtl)
#pragma unroll
      for (int r = 0; r < 4; ++r)
        H[((2 * wv + mtl) * 16 + quad * 4 + r) * 168 + nt * 16 + l15] = f2bf(celu01(acc0[nt][mtl][r]));
  __syncthreads();                                       // H0 visible / fence

  // ---------------- layer 1: 160 -> 128 --------------------------------------
  f32x4 acc1[8][2];
#pragma unroll
  for (int nt = 0; nt < 8; ++nt) {
    const float b = b1[t * 128 + nt * 16 + l15];
#pragma unroll
    for (int mtl = 0; mtl < 2; ++mtl) acc1[nt][mtl] = (f32x4){b, b, b, b};
  }
#pragma unroll
  for (int ks = 0; ks < 5; ++ks) {
    bf16x8 a[2];
#pragma unroll
    for (int mtl = 0; mtl < 2; ++mtl)
      a[mtl] = *(const bf16x8*)&H[((2 * wv + mtl) * 16 + l15) * 168 + quad * 8 + ks * 32];
#pragma unroll
    for (int nt = 0; nt < 8; ++nt) {
      const bf16x8 w = wb1[(ks * 8 + nt) * 64 + lane];
#pragma unroll
      for (int mtl = 0; mtl < 2; ++mtl)
        acc1[nt][mtl] = __builtin_amdgcn_mfma_f32_16x16x32_bf16(a[mtl], w, acc1[nt][mtl], 0, 0, 0);
    }
  }
  __syncthreads();                                       // all H0 reads done
#pragma unroll
  for (int nt = 0; nt < 8; ++nt)                         // H1: stride 136
#pragma unroll
    for (int mtl = 0; mtl < 2; ++mtl)
#pragma unroll
      for (int r = 0; r < 4; ++r)
        H[((2 * wv + mtl) * 16 + quad * 4 + r) * 136 + nt * 16 + l15] = f2bf(celu01(acc1[nt][mtl][r]));
  __syncthreads();                                       // H1 visible / fence

  // ---------------- layer 2: 128 -> 96 ---------------------------------------
  f32x4 acc2[6][2];
#pragma unroll
  for (int nt = 0; nt < 6; ++nt) {
    const float b = b2[t * 96 + nt * 16 + l15];
#pragma unroll
    for (int mtl = 0; mtl < 2; ++mtl) acc2[nt][mtl] = (f32x4){b, b, b, b};
  }
#pragma unroll
  for (int ks = 0; ks < 4; ++ks) {
    bf16x8 a[2];
#pragma unroll
    for (int mtl = 0; mtl < 2; ++mtl)
      a[mtl] = *(const bf16x8*)&H[((2 * wv + mtl) * 16 + l15) * 136 + quad * 8 + ks * 32];
#pragma unroll
    for (int nt = 0; nt < 6; ++nt) {
      const bf16x8 w = wb2[(ks * 6 + nt) * 64 + lane];
#pragma unroll
      for (int mtl = 0; mtl < 2; ++mtl)
        acc2[nt][mtl] = __builtin_amdgcn_mfma_f32_16x16x32_bf16(a[mtl], w, acc2[nt][mtl], 0, 0, 0);
    }
  }
  __syncthreads();                                       // all H1 reads done
#pragma unroll
  for (int nt = 0; nt < 6; ++nt)                         // H2: stride 104
#pragma unroll
    for (int mtl = 0; mtl < 2; ++mtl)
#pragma unroll
      for (int r = 0; r < 4; ++r)
        H[((2 * wv + mtl) * 16 + quad * 4 + r) * 104 + nt * 16 + l15] = f2bf(celu01(acc2[nt][mtl][r]));
  __syncthreads();                                       // H2 visible / fence

  // ---------------- layer 3: 96 -> 1 via MFMA (w3 broadcast to all 16 cols) --
  bf16x8 w3f[3];
#pragma unroll
  for (int ks = 0; ks < 3; ++ks) {
    const float* wp = W3 + t * 96 + ks * 32 + quad * 8;  // uniform across l15
    const float4 f0 = *(const float4*)wp;
    const float4 f1 = *(const float4*)(wp + 4);
    U8 c;
    c.u[0] = pk2(f0.x, f0.y);
    c.u[1] = pk2(f0.z, f0.w);
    c.u[2] = pk2(f1.x, f1.y);
    c.u[3] = pk2(f1.z, f1.w);
    w3f[ks] = c.v;
  }
  f32x4 accE[2];
#pragma unroll
  for (int mtl = 0; mtl < 2; ++mtl) accE[mtl] = (f32x4){0.f, 0.f, 0.f, 0.f};
#pragma unroll
  for (int mtl = 0; mtl < 2; ++mtl)
#pragma unroll
    for (int ks = 0; ks < 3; ++ks) {
      const bf16x8 a = *(const bf16x8*)&H[((2 * wv + mtl) * 16 + l15) * 104 + quad * 8 + ks * 32];
      accE[mtl] = __builtin_amdgcn_mfma_f32_16x16x32_bf16(a, w3f[ks], accE[mtl], 0, 0, 0);
    }
  // accE[mtl][r] = energy of atom (2wv+mtl)*16 + quad*4 + r, identical over l15
  const float bb3 = b3[t];
#pragma unroll
  for (int mtl = 0; mtl < 2; ++mtl)
#pragma unroll
    for (int r = 0; r < 4; ++r)
      if (l15 == 0) {
        const int ai = permS[(2 * wv + mtl) * 16 + quad * 4 + r];
        if (ai >= 0) atomicAdd(&outE[ai >> 6], accE[mtl][r] + bb3);
      }
}

// ---- launch -----------------------------------------------------------------

extern "C" void kernel_launch(void* const* d_in, const int* in_sizes, int n_in,
                              void* d_out, int out_size, void* d_ws, size_t ws_size,
                              hipStream_t stream)
{
  const int*   species = (const int*)d_in[0];
  const float* aev     = (const float*)d_in[1];
  const float* W0 = (const float*)d_in[2];
  const float* b0 = (const float*)d_in[3];
  const float* W1 = (const float*)d_in[4];
  const float* b1 = (const float*)d_in[5];
  const float* W2 = (const float*)d_in[6];
  const float* b2 = (const float*)d_in[7];
  const float* W3 = (const float*)d_in[8];
  const float* b3 = (const float*)d_in[9];
  float* out = (float*)d_out;

  // ws (ints): poff[8], hist[2048], perm[PADTOT]; then bf16 WB
  int* poff = (int*)d_ws;
  int* hist = poff + 8;
  int* perm = hist + NTYPES * NBLK_H;
  unsigned short* WB = (unsigned short*)(perm + PADTOT);

  k_pre<<<PADTOT / 256, 256, 0, stream>>>(species, out, perm, hist, W0, W1, W2, WB);
  k_sct<<<NBLK_H, 256, 0, stream>>>(species, hist, poff, perm);
  k_mlp<<<NBLK_MLP, 128, 0, stream>>>(aev, WB, b0, b1, b2, b3, W3,
                                      poff, perm, out + NATOMS);
}

// Round 11
// 357.563 us; speedup vs baseline: 1.3171x; 1.0034x over previous
//
#include <hip/hip_runtime.h>
#include <math.h>

// ANI per-type MLP ensemble, MI355X bf16-MFMA.
// R15: single-variable test of the scheduler-budget theory. All nine k_mlp
//      variants (serial reg loads / reg dbuf / LDS DMA / 1-4 waves) share one
//      invariant: ~5000 cyc per K-step ~= 11 serial load latencies -> MLP~=1.
//      R7's VGPR_Count=76 despite source-level double-buffering (230 regs
//      would have fit) shows the AMDGPU scheduler sinks loads to their uses
//      to chase max occupancy, regardless of source structure. R15 = R14 with
//      __launch_bounds__(128, 1) on k_mlp ONLY: min-waves/EU=1 raises the
//      register budget to 512, giving the scheduler room to batch the 10
//      unrolled weight loads + 8 aev loads per K-step ahead of the MFMA group.
//      Tell: VGPR_Count >= ~180 (hint honored). Everything else untouched
//      (3 launches, deterministic fused k_sct, proven ws layout).

#define NATOMS   131072                     // 2048 * 64
#define NMOL     2048
#define AEV      384
#define NTYPES   4
#define MBLK     64                         // atoms per MLP block
#define PADTOT   (NATOMS + NTYPES * MBLK)   // 131328
#define NBLK_MLP (PADTOT / MBLK)            // 2052
#define NBLK_H   512                        // histogram blocks (256 atoms each)

// swizzled-weight layout (bf16, per type): L0 [12kt][10nt][64][8] = 61440,
// L1 [5][8][64][8] = 20480, L2 [4][6][64][8] = 12288  -> 94208 per type
#define WB_L1 61440
#define WB_L2 81920
#define WB_T  94208

typedef __attribute__((ext_vector_type(8))) short bf16x8;
typedef __attribute__((ext_vector_type(4))) float f32x4;

__device__ __forceinline__ float celu01(float v) {
  return (v > 0.f) ? v : 0.1f * (__expf(v * 10.f) - 1.f);  // v<0 => exp arg <0, safe
}
__device__ __forceinline__ unsigned short f2bf(float x) {  // RNE
  unsigned u = __float_as_uint(x);
  return (unsigned short)((u + 0x7FFFu + ((u >> 16) & 1u)) >> 16);
}
__device__ __forceinline__ unsigned int pk2(float lo, float hi) {  // 2x RNE packed
  unsigned a = __float_as_uint(lo), b = __float_as_uint(hi);
  a = (a + 0x7FFFu + ((a >> 16) & 1u)) >> 16;
  b = ((b + 0x7FFFu + ((b >> 16) & 1u)) >> 16) << 16;
  return a | b;
}

// ---- fused prep: out init + perm init + weight swizzle + histogram ----------

__global__ void k_pre(const int* __restrict__ species, float* __restrict__ out,
                      int* __restrict__ perm, int* __restrict__ hist,
                      const float* __restrict__ W0, const float* __restrict__ W1,
                      const float* __restrict__ W2, unsigned short* __restrict__ WB) {
  const int tid = threadIdx.x, blk = blockIdx.x;
  const int i = blk * 256 + tid;                  // grid = PADTOT/256 = 513
  perm[i] = -1;
  if (i < NATOMS) out[i] = (float)species[i];     // output 0: species passthrough
  if (i < NMOL) out[NATOMS + i] = 0.f;            // output 1: energies

  // weight swizzle, grid-stride over 4*WB_T elements
  for (int f = i; f < NTYPES * WB_T; f += PADTOT) {
    const int t = f / WB_T, e0 = f - t * WB_T;
    int base, NT, N;
    const float* W;
    if (e0 < WB_L1)      { base = 0;     NT = 10; N = 160; W = W0 + (size_t)t * AEV * 160; }
    else if (e0 < WB_L2) { base = WB_L1; NT = 8;  N = 128; W = W1 + (size_t)t * 160 * 128; }
    else                 { base = WB_L2; NT = 6;  N = 96;  W = W2 + (size_t)t * 128 * 96; }
    const int e = e0 - base, frag = e >> 9, r = e & 511, lane = r >> 3, j = r & 7;
    const int kt = frag / NT, nt = frag - kt * NT;
    const int k = kt * 32 + ((lane >> 4) << 3) + j, n = nt * 16 + (lane & 15);
    WB[(size_t)t * WB_T + e0] = f2bf(W[k * N + n]);
  }

  if (blk < NBLK_H) {                             // histogram (blocks 0..511)
    const int sp = species[i];
    const int wv = tid >> 6;
    __shared__ int wc[4 * NTYPES];
#pragma unroll
    for (int t = 0; t < NTYPES; ++t) {
      const unsigned long long m = __ballot(sp == t);
      if ((tid & 63) == 0) wc[wv * NTYPES + t] = __popcll(m);
    }
    __syncthreads();
    if (tid < NTYPES)
      hist[tid * NBLK_H + blk] = wc[tid] + wc[4 + tid] + wc[8 + tid] + wc[12 + tid];
  }
}

// ---- k_sct: fused deterministic scan + scatter (replaces k_scan+k_scatter) --
// Every block redundantly computes: wave t reduces hist row t -> type total
// AND (same loads, idx<blk predicate) the exclusive prefix for THIS block.
// perm bit-identical to the R2 counting sort (preserves within-type ascending
// atom order -- R13 lesson). No atomics anywhere.

__global__ void k_sct(const int* __restrict__ species, const int* __restrict__ hist,
                      int* __restrict__ poff, int* __restrict__ perm) {
  __shared__ int tot[NTYPES], preS[NTYPES], bofS[NTYPES];
  const int tid = threadIdx.x, blk = blockIdx.x;
  const int wv = tid >> 6, lane = tid & 63;

  int s = 0, p = 0;                               // wave wv handles type wv
  for (int c = 0; c < 8; ++c) {
    const int idx = c * 64 + lane;
    const int h = hist[wv * NBLK_H + idx];
    s += h;
    if (idx < blk) p += h;
  }
  for (int off = 32; off; off >>= 1) {
    s += __shfl_down(s, off);
    p += __shfl_down(p, off);
  }
  if (lane == 0) { tot[wv] = s; preS[wv] = p; }
  __syncthreads();
  if (tid == 0) {
    int acc = 0;
    for (int t = 0; t < NTYPES; ++t) {
      bofS[t] = acc + preS[t];                    // base[t] + excl. prefix(<blk)
      acc += ((tot[t] + 63) >> 6) << 6;
      if (blk == 0) poff[t + 1] = acc;            // publish padded prefix
    }
    if (blk == 0) poff[0] = 0;
  }
  __syncthreads();

  const int i = blk * 256 + tid;                  // grid = NATOMS/256 = 512
  const int sp = species[i];
  __shared__ int wc[4 * NTYPES];
  unsigned long long msel = 0;
#pragma unroll
  for (int t = 0; t < NTYPES; ++t) {
    const unsigned long long m = __ballot(sp == t);
    if ((tid & 63) == 0) wc[wv * NTYPES + t] = __popcll(m);
    if (sp == t) msel = m;
  }
  __syncthreads();
  int woff = 0;
  for (int w = 0; w < wv; ++w) woff += wc[w * NTYPES + sp];
  const int rk = __builtin_amdgcn_mbcnt_hi((unsigned)(msel >> 32),
                 __builtin_amdgcn_mbcnt_lo((unsigned)msel, 0));
  perm[bofS[sp] + woff + rk] = i;
}

// ---- 2-wave fused 4-layer MFMA MLP + molecule reduction ---------------------
// 128 threads = 2 waves; wave w owns M-tiles {2w, 2w+1} = rows [32w, 32w+32).
// __launch_bounds__(128, 1): min-waves/EU = 1 -> register budget up to 512 so
// the scheduler can batch the per-K-step loads (10 weight + 8 aev) ahead of
// the MFMA group instead of sinking each to its use (max-occupancy default).

__global__ __launch_bounds__(128, 1) void k_mlp(
    const float* __restrict__ aev, const unsigned short* __restrict__ WB,
    const float* __restrict__ b0, const float* __restrict__ b1,
    const float* __restrict__ b2, const float* __restrict__ b3,
    const float* __restrict__ W3,
    const int* __restrict__ poff, const int* __restrict__ perm,
    float* __restrict__ outE)
{
  __shared__ __align__(16) unsigned short H[64 * 168];   // 21504 B
  __shared__ int permS[64];

  const int tid  = threadIdx.x;
  const int lane = tid & 63;
  const int wv   = __builtin_amdgcn_readfirstlane(tid >> 6);   // 0 / 1
  const int quad = lane >> 4, l15 = lane & 15;
  const int slot0 = blockIdx.x * MBLK;

  if (tid < 64) permS[tid] = perm[slot0 + tid];
  int t_ = (slot0 >= poff[1]) + (slot0 >= poff[2]) + (slot0 >= poff[3]);
  if (t_ > 3) t_ = 3;
  const int t = __builtin_amdgcn_readfirstlane(t_);
  __syncthreads();

  // per-M-tile row pointers (padded rows -> aev row 0; results discarded)
  const float* rp[2];
#pragma unroll
  for (int mtl = 0; mtl < 2; ++mtl) {
    const int ai = permS[(2 * wv + mtl) * 16 + l15];
    rp[mtl] = aev + (size_t)(ai < 0 ? 0 : ai) * AEV + quad * 8;
  }

  const bf16x8* wb0 = (const bf16x8*)(WB + (size_t)t * WB_T);
  const bf16x8* wb1 = (const bf16x8*)(WB + (size_t)t * WB_T + WB_L1);
  const bf16x8* wb2 = (const bf16x8*)(WB + (size_t)t * WB_T + WB_L2);

  union U8 { unsigned int u[4]; bf16x8 v; };

  // ---------------- layer 0: 384 -> 160 --------------------------------------
  f32x4 acc0[10][2];
#pragma unroll
  for (int nt = 0; nt < 10; ++nt) {
    const float b = b0[t * 160 + nt * 16 + l15];
#pragma unroll
    for (int mtl = 0; mtl < 2; ++mtl) acc0[nt][mtl] = (f32x4){b, b, b, b};
  }

  float4 raw[2][2];
#pragma unroll
  for (int mtl = 0; mtl < 2; ++mtl) {                    // prologue: ks = 0
    raw[mtl][0] = *(const float4*)(rp[mtl]);
    raw[mtl][1] = *(const float4*)(rp[mtl] + 4);
  }

  for (int ks = 0; ks < 12; ++ks) {
    bf16x8 a[2];
#pragma unroll
    for (int mtl = 0; mtl < 2; ++mtl) {                  // convert current
      U8 c;
      c.u[0] = pk2(raw[mtl][0].x, raw[mtl][0].y);
      c.u[1] = pk2(raw[mtl][0].z, raw[mtl][0].w);
      c.u[2] = pk2(raw[mtl][1].x, raw[mtl][1].y);
      c.u[3] = pk2(raw[mtl][1].z, raw[mtl][1].w);
      a[mtl] = c.v;
    }
    if (ks < 11) {                                       // prefetch next K-slice
#pragma unroll
      for (int mtl = 0; mtl < 2; ++mtl) {
        const float* p = rp[mtl] + (ks + 1) * 32;
        raw[mtl][0] = *(const float4*)p;
        raw[mtl][1] = *(const float4*)(p + 4);
      }
    }
#pragma unroll
    for (int nt = 0; nt < 10; ++nt) {
      const bf16x8 w = wb0[(ks * 10 + nt) * 64 + lane];  // one load -> 2 MFMAs
#pragma unroll
      for (int mtl = 0; mtl < 2; ++mtl)
        acc0[nt][mtl] = __builtin_amdgcn_mfma_f32_16x16x32_bf16(a[mtl], w, acc0[nt][mtl], 0, 0, 0);
    }
  }
#pragma unroll
  for (int nt = 0; nt < 10; ++nt)                        // H0: stride 168
#pragma unroll
    for (int mtl = 0; mtl < 2; ++mtl)
#pragma unroll
      for (int r = 0; r < 4; ++r)
        H[((2 * wv + mtl) * 16 + quad * 4 + r) * 168 + nt * 16 + l15] = f2bf(celu01(acc0[nt][mtl][r]));
  __syncthreads();                                       // H0 visible / fence

  // ---------------- layer 1: 160 -> 128 --------------------------------------
  f32x4 acc1[8][2];
#pragma unroll
  for (int nt = 0; nt < 8; ++nt) {
    const float b = b1[t * 128 + nt * 16 + l15];
#pragma unroll
    for (int mtl = 0; mtl < 2; ++mtl) acc1[nt][mtl] = (f32x4){b, b, b, b};
  }
#pragma unroll
  for (int ks = 0; ks < 5; ++ks) {
    bf16x8 a[2];
#pragma unroll
    for (int mtl = 0; mtl < 2; ++mtl)
      a[mtl] = *(const bf16x8*)&H[((2 * wv + mtl) * 16 + l15) * 168 + quad * 8 + ks * 32];
#pragma unroll
    for (int nt = 0; nt < 8; ++nt) {
      const bf16x8 w = wb1[(ks * 8 + nt) * 64 + lane];
#pragma unroll
      for (int mtl = 0; mtl < 2; ++mtl)
        acc1[nt][mtl] = __builtin_amdgcn_mfma_f32_16x16x32_bf16(a[mtl], w, acc1[nt][mtl], 0, 0, 0);
    }
  }
  __syncthreads();                                       // all H0 reads done
#pragma unroll
  for (int nt = 0; nt < 8; ++nt)                         // H1: stride 136
#pragma unroll
    for (int mtl = 0; mtl < 2; ++mtl)
#pragma unroll
      for (int r = 0; r < 4; ++r)
        H[((2 * wv + mtl) * 16 + quad * 4 + r) * 136 + nt * 16 + l15] = f2bf(celu01(acc1[nt][mtl][r]));
  __syncthreads();                                       // H1 visible / fence

  // ---------------- layer 2: 128 -> 96 ---------------------------------------
  f32x4 acc2[6][2];
#pragma unroll
  for (int nt = 0; nt < 6; ++nt) {
    const float b = b2[t * 96 + nt * 16 + l15];
#pragma unroll
    for (int mtl = 0; mtl < 2; ++mtl) acc2[nt][mtl] = (f32x4){b, b, b, b};
  }
#pragma unroll
  for (int ks = 0; ks < 4; ++ks) {
    bf16x8 a[2];
#pragma unroll
    for (int mtl = 0; mtl < 2; ++mtl)
      a[mtl] = *(const bf16x8*)&H[((2 * wv + mtl) * 16 + l15) * 136 + quad * 8 + ks * 32];
#pragma unroll
    for (int nt = 0; nt < 6; ++nt) {
      const bf16x8 w = wb2[(ks * 6 + nt) * 64 + lane];
#pragma unroll
      for (int mtl = 0; mtl < 2; ++mtl)
        acc2[nt][mtl] = __builtin_amdgcn_mfma_f32_16x16x32_bf16(a[mtl], w, acc2[nt][mtl], 0, 0, 0);
    }
  }
  __syncthreads();                                       // all H1 reads done
#pragma unroll
  for (int nt = 0; nt < 6; ++nt)                         // H2: stride 104
#pragma unroll
    for (int mtl = 0; mtl < 2; ++mtl)
#pragma unroll
      for (int r = 0; r < 4; ++r)
        H[((2 * wv + mtl) * 16 + quad * 4 + r) * 104 + nt * 16 + l15] = f2bf(celu01(acc2[nt][mtl][r]));
  __syncthreads();                                       // H2 visible / fence

  // ---------------- layer 3: 96 -> 1 via MFMA (w3 broadcast to all 16 cols) --
  bf16x8 w3f[3];
#pragma unroll
  for (int ks = 0; ks < 3; ++ks) {
    const float* wp = W3 + t * 96 + ks * 32 + quad * 8;  // uniform across l15
    const float4 f0 = *(const float4*)wp;
    const float4 f1 = *(const float4*)(wp + 4);
    U8 c;
    c.u[0] = pk2(f0.x, f0.y);
    c.u[1] = pk2(f0.z, f0.w);
    c.u[2] = pk2(f1.x, f1.y);
    c.u[3] = pk2(f1.z, f1.w);
    w3f[ks] = c.v;
  }
  f32x4 accE[2];
#pragma unroll
  for (int mtl = 0; mtl < 2; ++mtl) accE[mtl] = (f32x4){0.f, 0.f, 0.f, 0.f};
#pragma unroll
  for (int mtl = 0; mtl < 2; ++mtl)
#pragma unroll
    for (int ks = 0; ks < 3; ++ks) {
      const bf16x8 a = *(const bf16x8*)&H[((2 * wv + mtl) * 16 + l15) * 104 + quad * 8 + ks * 32];
      accE[mtl] = __builtin_amdgcn_mfma_f32_16x16x32_bf16(a, w3f[ks], accE[mtl], 0, 0, 0);
    }
  // accE[mtl][r] = energy of atom (2wv+mtl)*16 + quad*4 + r, identical over l15
  const float bb3 = b3[t];
#pragma unroll
  for (int mtl = 0; mtl < 2; ++mtl)
#pragma unroll
    for (int r = 0; r < 4; ++r)
      if (l15 == 0) {
        const int ai = permS[(2 * wv + mtl) * 16 + quad * 4 + r];
        if (ai >= 0) atomicAdd(&outE[ai >> 6], accE[mtl][r] + bb3);
      }
}

// ---- launch -----------------------------------------------------------------

extern "C" void kernel_launch(void* const* d_in, const int* in_sizes, int n_in,
                              void* d_out, int out_size, void* d_ws, size_t ws_size,
                              hipStream_t stream)
{
  const int*   species = (const int*)d_in[0];
  const float* aev     = (const float*)d_in[1];
  const float* W0 = (const float*)d_in[2];
  const float* b0 = (const float*)d_in[3];
  const float* W1 = (const float*)d_in[4];
  const float* b1 = (const float*)d_in[5];
  const float* W2 = (const float*)d_in[6];
  const float* b2 = (const float*)d_in[7];
  const float* W3 = (const float*)d_in[8];
  const float* b3 = (const float*)d_in[9];
  float* out = (float*)d_out;

  // ws (ints): poff[8], hist[2048], perm[PADTOT]; then bf16 WB
  int* poff = (int*)d_ws;
  int* hist = poff + 8;
  int* perm = hist + NTYPES * NBLK_H;
  unsigned short* WB = (unsigned short*)(perm + PADTOT);

  k_pre<<<PADTOT / 256, 256, 0, stream>>>(species, out, perm, hist, W0, W1, W2, WB);
  k_sct<<<NBLK_H, 256, 0, stream>>>(species, hist, poff, perm);
  k_mlp<<<NBLK_MLP, 128, 0, stream>>>(aev, WB, b0, b1, b2, b3, W3,
                                      poff, perm, out + NATOMS);
}

// Round 12
// 340.716 us; speedup vs baseline: 1.3822x; 1.0494x over previous
//
#include <hip/hip_runtime.h>
#include <math.h>

// ANI per-type MLP ensemble, MI355X bf16-MFMA.
// R16: R7's explicit weight double-buffer, PINNED with sched_barrier(0).
//      R15 refuted the budget theory (launch_bounds(128,1) -> VGPR stayed 100,
//      time flat): the scheduler sinks loads to uses regardless of headroom.
//      R7's dbuf dissolved (VGPR=76) because nothing fenced the sinking.
//      R16 per K-step: { issue next-step weight loads into WN ;
//      sched_barrier(0) ; cvt + aev prefetch + MFMA group on WC }.
//      The fence forces the loads to issue ahead of the MFMA group, keeping
//      both buffers live (compiler must allocate ~80 regs for them) and
//      auto-generating counted vmcnt waits (T4 pattern, compiler-inserted --
//      the hand-asm version miscompiled in R11). Same for L1 (8-wide) and
//      L2 (6-wide). Tell: VGPR_Count ~190-230 = buffers survived.
//      Everything else = R14/R15 (3 launches, fused deterministic k_sct,
//      proven ws layout, H strides 168/136/104, epilogue, numerics).

#define NATOMS   131072                     // 2048 * 64
#define NMOL     2048
#define AEV      384
#define NTYPES   4
#define MBLK     64                         // atoms per MLP block
#define PADTOT   (NATOMS + NTYPES * MBLK)   // 131328
#define NBLK_MLP (PADTOT / MBLK)            // 2052
#define NBLK_H   512                        // histogram blocks (256 atoms each)

// swizzled-weight layout (bf16, per type): L0 [12kt][10nt][64][8] = 61440,
// L1 [5][8][64][8] = 20480, L2 [4][6][64][8] = 12288  -> 94208 per type
#define WB_L1 61440
#define WB_L2 81920
#define WB_T  94208

typedef __attribute__((ext_vector_type(8))) short bf16x8;
typedef __attribute__((ext_vector_type(4))) float f32x4;

__device__ __forceinline__ float celu01(float v) {
  return (v > 0.f) ? v : 0.1f * (__expf(v * 10.f) - 1.f);  // v<0 => exp arg <0, safe
}
__device__ __forceinline__ unsigned short f2bf(float x) {  // RNE
  unsigned u = __float_as_uint(x);
  return (unsigned short)((u + 0x7FFFu + ((u >> 16) & 1u)) >> 16);
}
__device__ __forceinline__ unsigned int pk2(float lo, float hi) {  // 2x RNE packed
  unsigned a = __float_as_uint(lo), b = __float_as_uint(hi);
  a = (a + 0x7FFFu + ((a >> 16) & 1u)) >> 16;
  b = ((b + 0x7FFFu + ((b >> 16) & 1u)) >> 16) << 16;
  return a | b;
}
__device__ __forceinline__ bf16x8 cvt8(const float4 r0, const float4 r1) {
  union { unsigned int u[4]; bf16x8 v; } c;
  c.u[0] = pk2(r0.x, r0.y);
  c.u[1] = pk2(r0.z, r0.w);
  c.u[2] = pk2(r1.x, r1.y);
  c.u[3] = pk2(r1.z, r1.w);
  return c.v;
}

// ---- fused prep: out init + perm init + weight swizzle + histogram ----------

__global__ void k_pre(const int* __restrict__ species, float* __restrict__ out,
                      int* __restrict__ perm, int* __restrict__ hist,
                      const float* __restrict__ W0, const float* __restrict__ W1,
                      const float* __restrict__ W2, unsigned short* __restrict__ WB) {
  const int tid = threadIdx.x, blk = blockIdx.x;
  const int i = blk * 256 + tid;                  // grid = PADTOT/256 = 513
  perm[i] = -1;
  if (i < NATOMS) out[i] = (float)species[i];     // output 0: species passthrough
  if (i < NMOL) out[NATOMS + i] = 0.f;            // output 1: energies

  // weight swizzle, grid-stride over 4*WB_T elements
  for (int f = i; f < NTYPES * WB_T; f += PADTOT) {
    const int t = f / WB_T, e0 = f - t * WB_T;
    int base, NT, N;
    const float* W;
    if (e0 < WB_L1)      { base = 0;     NT = 10; N = 160; W = W0 + (size_t)t * AEV * 160; }
    else if (e0 < WB_L2) { base = WB_L1; NT = 8;  N = 128; W = W1 + (size_t)t * 160 * 128; }
    else                 { base = WB_L2; NT = 6;  N = 96;  W = W2 + (size_t)t * 128 * 96; }
    const int e = e0 - base, frag = e >> 9, r = e & 511, lane = r >> 3, j = r & 7;
    const int kt = frag / NT, nt = frag - kt * NT;
    const int k = kt * 32 + ((lane >> 4) << 3) + j, n = nt * 16 + (lane & 15);
    WB[(size_t)t * WB_T + e0] = f2bf(W[k * N + n]);
  }

  if (blk < NBLK_H) {                             // histogram (blocks 0..511)
    const int sp = species[i];
    const int wv = tid >> 6;
    __shared__ int wc[4 * NTYPES];
#pragma unroll
    for (int t = 0; t < NTYPES; ++t) {
      const unsigned long long m = __ballot(sp == t);
      if ((tid & 63) == 0) wc[wv * NTYPES + t] = __popcll(m);
    }
    __syncthreads();
    if (tid < NTYPES)
      hist[tid * NBLK_H + blk] = wc[tid] + wc[4 + tid] + wc[8 + tid] + wc[12 + tid];
  }
}

// ---- k_sct: fused deterministic scan + scatter ------------------------------
// Every block redundantly computes: wave t reduces hist row t -> type total
// AND (same loads, idx<blk predicate) the exclusive prefix for THIS block.
// perm bit-identical to the R2 counting sort. No atomics anywhere.

__global__ void k_sct(const int* __restrict__ species, const int* __restrict__ hist,
                      int* __restrict__ poff, int* __restrict__ perm) {
  __shared__ int tot[NTYPES], preS[NTYPES], bofS[NTYPES];
  const int tid = threadIdx.x, blk = blockIdx.x;
  const int wv = tid >> 6, lane = tid & 63;

  int s = 0, p = 0;                               // wave wv handles type wv
  for (int c = 0; c < 8; ++c) {
    const int idx = c * 64 + lane;
    const int h = hist[wv * NBLK_H + idx];
    s += h;
    if (idx < blk) p += h;
  }
  for (int off = 32; off; off >>= 1) {
    s += __shfl_down(s, off);
    p += __shfl_down(p, off);
  }
  if (lane == 0) { tot[wv] = s; preS[wv] = p; }
  __syncthreads();
  if (tid == 0) {
    int acc = 0;
    for (int t = 0; t < NTYPES; ++t) {
      bofS[t] = acc + preS[t];                    // base[t] + excl. prefix(<blk)
      acc += ((tot[t] + 63) >> 6) << 6;
      if (blk == 0) poff[t + 1] = acc;            // publish padded prefix
    }
    if (blk == 0) poff[0] = 0;
  }
  __syncthreads();

  const int i = blk * 256 + tid;                  // grid = NATOMS/256 = 512
  const int sp = species[i];
  __shared__ int wc[4 * NTYPES];
  unsigned long long msel = 0;
#pragma unroll
  for (int t = 0; t < NTYPES; ++t) {
    const unsigned long long m = __ballot(sp == t);
    if ((tid & 63) == 0) wc[wv * NTYPES + t] = __popcll(m);
    if (sp == t) msel = m;
  }
  __syncthreads();
  int woff = 0;
  for (int w = 0; w < wv; ++w) woff += wc[w * NTYPES + sp];
  const int rk = __builtin_amdgcn_mbcnt_hi((unsigned)(msel >> 32),
                 __builtin_amdgcn_mbcnt_lo((unsigned)msel, 0));
  perm[bofS[sp] + woff + rk] = i;
}

// ---- 2-wave fused 4-layer MFMA MLP, sched_barrier-pinned weight dbuf --------
// 128 threads = 2 waves; wave w owns M-tiles {2w, 2w+1} = rows [32w, 32w+32).
// Per K-step: issue next-step weight loads into the OTHER buffer, then
// sched_barrier(0) (loads cannot sink past it), then cvt/ds_read + MFMA group
// on the current buffer. Forces both buffers live -> MLP ~10 instead of ~1.

__global__ __launch_bounds__(128, 1) void k_mlp(
    const float* __restrict__ aev, const unsigned short* __restrict__ WB,
    const float* __restrict__ b0, const float* __restrict__ b1,
    const float* __restrict__ b2, const float* __restrict__ b3,
    const float* __restrict__ W3,
    const int* __restrict__ poff, const int* __restrict__ perm,
    float* __restrict__ outE)
{
  __shared__ __align__(16) unsigned short H[64 * 168];   // 21504 B
  __shared__ int permS[64];

  const int tid  = threadIdx.x;
  const int lane = tid & 63;
  const int wv   = __builtin_amdgcn_readfirstlane(tid >> 6);   // 0 / 1
  const int quad = lane >> 4, l15 = lane & 15;
  const int slot0 = blockIdx.x * MBLK;

  if (tid < 64) permS[tid] = perm[slot0 + tid];
  int t_ = (slot0 >= poff[1]) + (slot0 >= poff[2]) + (slot0 >= poff[3]);
  if (t_ > 3) t_ = 3;
  const int t = __builtin_amdgcn_readfirstlane(t_);
  __syncthreads();

  // per-M-tile row pointers (padded rows -> aev row 0; results discarded)
  const float* rp[2];
#pragma unroll
  for (int mtl = 0; mtl < 2; ++mtl) {
    const int ai = permS[(2 * wv + mtl) * 16 + l15];
    rp[mtl] = aev + (size_t)(ai < 0 ? 0 : ai) * AEV + quad * 8;
  }

  const bf16x8* wb0 = (const bf16x8*)(WB + (size_t)t * WB_T);
  const bf16x8* wb1 = (const bf16x8*)(WB + (size_t)t * WB_T + WB_L1);
  const bf16x8* wb2 = (const bf16x8*)(WB + (size_t)t * WB_T + WB_L2);

  // ---------------- layer 0: 384 -> 160 --------------------------------------
  f32x4 acc0[10][2];
#pragma unroll
  for (int nt = 0; nt < 10; ++nt) {
    const float b = b0[t * 160 + nt * 16 + l15];
#pragma unroll
    for (int mtl = 0; mtl < 2; ++mtl) acc0[nt][mtl] = (f32x4){b, b, b, b};
  }

  bf16x8 wA[10], wB[10];
  float4 rA[2][2], rB[2][2];
#pragma unroll
  for (int nt = 0; nt < 10; ++nt) wA[nt] = wb0[nt * 64 + lane];   // ks=0 weights
#pragma unroll
  for (int m = 0; m < 2; ++m) {                                    // ks=0,1 aev
    rA[m][0] = *(const float4*)(rp[m]);
    rA[m][1] = *(const float4*)(rp[m] + 4);
    rB[m][0] = *(const float4*)(rp[m] + 32);
    rB[m][1] = *(const float4*)(rp[m] + 36);
  }

  // step: issue weight loads (ks+1) -> FENCE -> cvt + aev prefetch (ks+2) +
  // MFMA group on current buffer. Fence keeps the load batch ahead of the
  // MFMAs -> both buffers live, counted-vmcnt waits auto-inserted.
#define L0_STEP(KS, WC, WN, RC, PFW, PFR)                                      \
  {                                                                            \
    if (PFW) {                                                                 \
      _Pragma("unroll")                                                        \
      for (int nt = 0; nt < 10; ++nt)                                          \
        WN[nt] = wb0[((KS + 1) * 10 + nt) * 64 + lane];                        \
    }                                                                          \
    __builtin_amdgcn_sched_barrier(0);                                         \
    const bf16x8 a0 = cvt8(RC[0][0], RC[0][1]);                                \
    const bf16x8 a1 = cvt8(RC[1][0], RC[1][1]);                                \
    if (PFR) {                                                                 \
      _Pragma("unroll")                                                        \
      for (int m = 0; m < 2; ++m) {                                            \
        const float* p = rp[m] + (KS + 2) * 32;                                \
        RC[m][0] = *(const float4*)p;                                          \
        RC[m][1] = *(const float4*)(p + 4);                                    \
      }                                                                        \
    }                                                                          \
    _Pragma("unroll")                                                          \
    for (int nt = 0; nt < 10; ++nt) {                                          \
      acc0[nt][0] = __builtin_amdgcn_mfma_f32_16x16x32_bf16(a0, WC[nt], acc0[nt][0], 0, 0, 0); \
      acc0[nt][1] = __builtin_amdgcn_mfma_f32_16x16x32_bf16(a1, WC[nt], acc0[nt][1], 0, 0, 0); \
    }                                                                          \
  }

  L0_STEP(0,  wA, wB, rA, 1, 1)
  L0_STEP(1,  wB, wA, rB, 1, 1)
  L0_STEP(2,  wA, wB, rA, 1, 1)
  L0_STEP(3,  wB, wA, rB, 1, 1)
  L0_STEP(4,  wA, wB, rA, 1, 1)
  L0_STEP(5,  wB, wA, rB, 1, 1)
  L0_STEP(6,  wA, wB, rA, 1, 1)
  L0_STEP(7,  wB, wA, rB, 1, 1)
  L0_STEP(8,  wA, wB, rA, 1, 1)
  L0_STEP(9,  wB, wA, rB, 1, 1)   // PFR loads ks=11 into rB
  L0_STEP(10, wA, wB, rA, 1, 0)   // PFW loads ks=11 weights into wB
  L0_STEP(11, wB, wA, rB, 0, 0)
#undef L0_STEP

#pragma unroll
  for (int nt = 0; nt < 10; ++nt)                        // H0: stride 168
#pragma unroll
    for (int mtl = 0; mtl < 2; ++mtl)
#pragma unroll
      for (int r = 0; r < 4; ++r)
        H[((2 * wv + mtl) * 16 + quad * 4 + r) * 168 + nt * 16 + l15] = f2bf(celu01(acc0[nt][mtl][r]));
  __syncthreads();                                       // H0 visible / fence

  // ---------------- layer 1: 160 -> 128 --------------------------------------
  f32x4 acc1[8][2];
#pragma unroll
  for (int nt = 0; nt < 8; ++nt) {
    const float b = b1[t * 128 + nt * 16 + l15];
#pragma unroll
    for (int mtl = 0; mtl < 2; ++mtl) acc1[nt][mtl] = (f32x4){b, b, b, b};
  }
  bf16x8 w1A[8], w1B[8];
#pragma unroll
  for (int nt = 0; nt < 8; ++nt) w1A[nt] = wb1[nt * 64 + lane];

#define L1_STEP(KS, WC, WN, PFW)                                               \
  {                                                                            \
    if (PFW) {                                                                 \
      _Pragma("unroll")                                                        \
      for (int nt = 0; nt < 8; ++nt)                                           \
        WN[nt] = wb1[((KS + 1) * 8 + nt) * 64 + lane];                         \
    }                                                                          \
    __builtin_amdgcn_sched_barrier(0);                                         \
    const bf16x8 a0 = *(const bf16x8*)&H[((2 * wv + 0) * 16 + l15) * 168 + quad * 8 + (KS) * 32]; \
    const bf16x8 a1 = *(const bf16x8*)&H[((2 * wv + 1) * 16 + l15) * 168 + quad * 8 + (KS) * 32]; \
    _Pragma("unroll")                                                          \
    for (int nt = 0; nt < 8; ++nt) {                                           \
      acc1[nt][0] = __builtin_amdgcn_mfma_f32_16x16x32_bf16(a0, WC[nt], acc1[nt][0], 0, 0, 0); \
      acc1[nt][1] = __builtin_amdgcn_mfma_f32_16x16x32_bf16(a1, WC[nt], acc1[nt][1], 0, 0, 0); \
    }                                                                          \
  }

  L1_STEP(0, w1A, w1B, 1)
  L1_STEP(1, w1B, w1A, 1)
  L1_STEP(2, w1A, w1B, 1)
  L1_STEP(3, w1B, w1A, 1)
  L1_STEP(4, w1A, w1B, 0)
#undef L1_STEP

  __syncthreads();                                       // all H0 reads done
#pragma unroll
  for (int nt = 0; nt < 8; ++nt)                         // H1: stride 136
#pragma unroll
    for (int mtl = 0; mtl < 2; ++mtl)
#pragma unroll
      for (int r = 0; r < 4; ++r)
        H[((2 * wv + mtl) * 16 + quad * 4 + r) * 136 + nt * 16 + l15] = f2bf(celu01(acc1[nt][mtl][r]));
  __syncthreads();                                       // H1 visible / fence

  // ---------------- layer 2: 128 -> 96 ---------------------------------------
  f32x4 acc2[6][2];
#pragma unroll
  for (int nt = 0; nt < 6; ++nt) {
    const float b = b2[t * 96 + nt * 16 + l15];
#pragma unroll
    for (int mtl = 0; mtl < 2; ++mtl) acc2[nt][mtl] = (f32x4){b, b, b, b};
  }
  bf16x8 w2A[6], w2B[6];
#pragma unroll
  for (int nt = 0; nt < 6; ++nt) w2A[nt] = wb2[nt * 64 + lane];

#define L2_STEP(KS, WC, WN, PFW)                                               \
  {                                                                            \
    if (PFW) {                                                                 \
      _Pragma("unroll")                                                        \
      for (int nt = 0; nt < 6; ++nt)                                           \
        WN[nt] = wb2[((KS + 1) * 6 + nt) * 64 + lane];                         \
    }                                                                          \
    __builtin_amdgcn_sched_barrier(0);                                         \
    const bf16x8 a0 = *(const bf16x8*)&H[((2 * wv + 0) * 16 + l15) * 136 + quad * 8 + (KS) * 32]; \
    const bf16x8 a1 = *(const bf16x8*)&H[((2 * wv + 1) * 16 + l15) * 136 + quad * 8 + (KS) * 32]; \
    _Pragma("unroll")                                                          \
    for (int nt = 0; nt < 6; ++nt) {                                           \
      acc2[nt][0] = __builtin_amdgcn_mfma_f32_16x16x32_bf16(a0, WC[nt], acc2[nt][0], 0, 0, 0); \
      acc2[nt][1] = __builtin_amdgcn_mfma_f32_16x16x32_bf16(a1, WC[nt], acc2[nt][1], 0, 0, 0); \
    }                                                                          \
  }

  L2_STEP(0, w2A, w2B, 1)
  L2_STEP(1, w2B, w2A, 1)
  L2_STEP(2, w2A, w2B, 1)
  L2_STEP(3, w2B, w2A, 0)
#undef L2_STEP

  __syncthreads();                                       // all H1 reads done
#pragma unroll
  for (int nt = 0; nt < 6; ++nt)                         // H2: stride 104
#pragma unroll
    for (int mtl = 0; mtl < 2; ++mtl)
#pragma unroll
      for (int r = 0; r < 4; ++r)
        H[((2 * wv + mtl) * 16 + quad * 4 + r) * 104 + nt * 16 + l15] = f2bf(celu01(acc2[nt][mtl][r]));
  __syncthreads();                                       // H2 visible / fence

  // ---------------- layer 3: 96 -> 1 via MFMA (w3 broadcast to all 16 cols) --
  bf16x8 w3f[3];
#pragma unroll
  for (int ks = 0; ks < 3; ++ks) {
    const float* wp = W3 + t * 96 + ks * 32 + quad * 8;  // uniform across l15
    const float4 f0 = *(const float4*)wp;
    const float4 f1 = *(const float4*)(wp + 4);
    w3f[ks] = cvt8(f0, f1);
  }
  f32x4 accE[2];
#pragma unroll
  for (int mtl = 0; mtl < 2; ++mtl) accE[mtl] = (f32x4){0.f, 0.f, 0.f, 0.f};
#pragma unroll
  for (int mtl = 0; mtl < 2; ++mtl)
#pragma unroll
    for (int ks = 0; ks < 3; ++ks) {
      const bf16x8 a = *(const bf16x8*)&H[((2 * wv + mtl) * 16 + l15) * 104 + quad * 8 + ks * 32];
      accE[mtl] = __builtin_amdgcn_mfma_f32_16x16x32_bf16(a, w3f[ks], accE[mtl], 0, 0, 0);
    }
  // accE[mtl][r] = energy of atom (2wv+mtl)*16 + quad*4 + r, identical over l15
  const float bb3 = b3[t];
#pragma unroll
  for (int mtl = 0; mtl < 2; ++mtl)
#pragma unroll
    for (int r = 0; r < 4; ++r)
      if (l15 == 0) {
        const int ai = permS[(2 * wv + mtl) * 16 + quad * 4 + r];
        if (ai >= 0) atomicAdd(&outE[ai >> 6], accE[mtl][r] + bb3);
      }
}

// ---- launch -----------------------------------------------------------------

extern "C" void kernel_launch(void* const* d_in, const int* in_sizes, int n_in,
                              void* d_out, int out_size, void* d_ws, size_t ws_size,
                              hipStream_t stream)
{
  const int*   species = (const int*)d_in[0];
  const float* aev     = (const float*)d_in[1];
  const float* W0 = (const float*)d_in[2];
  const float* b0 = (const float*)d_in[3];
  const float* W1 = (const float*)d_in[4];
  const float* b1 = (const float*)d_in[5];
  const float* W2 = (const float*)d_in[6];
  const float* b2 = (const float*)d_in[7];
  const float* W3 = (const float*)d_in[8];
  const float* b3 = (const float*)d_in[9];
  float* out = (float*)d_out;

  // ws (ints): poff[8], hist[2048], perm[PADTOT]; then bf16 WB
  int* poff = (int*)d_ws;
  int* hist = poff + 8;
  int* perm = hist + NTYPES * NBLK_H;
  unsigned short* WB = (unsigned short*)(perm + PADTOT);

  k_pre<<<PADTOT / 256, 256, 0, stream>>>(species, out, perm, hist, W0, W1, W2, WB);
  k_sct<<<NBLK_H, 256, 0, stream>>>(species, hist, poff, perm);
  k_mlp<<<NBLK_MLP, 128, 0, stream>>>(aev, WB, b0, b1, b2, b3, W3,
                                      poff, perm, out + NATOMS);
}